// Round 10
// baseline (218.803 us; speedup 1.0000x reference)
//
#include <hip/hip_runtime.h>

// VQ: N=262144 vectors (64x4096), D=64, K=512 codewords, fp32.
// out (float32): quantized[16777216] | indices[262144] (as float) | loss[1]
//
// R18 = R17 with the per-block critical path fixed (staging + conflicts).
//  R17 post-mortem: clean compile (VGPR 64, FETCH 67/WRITE 70 MB) but dur
//  stuck at 132us with all pipes <35% and occ 24% -- stall-bound: 16
//  barrier-separated phases/block with exposed stage latency + 6.29M LDS
//  bank-conflict cycles. Occupancy experiments (R12..R17) show dur does
//  NOT track static residency; fix the critical path instead:
//   - global_load_lds double-buffer (register-free T14): 2x16KB buffers,
//     4x1KB fire-and-forget copies per wave for chunk ch+1 issued right
//     after the barrier, compute chunk ch meanwhile. Barriers 16->8,
//     stage latency hidden. No long-lived VGPRs (R16 spill impossible).
//   - T2 XOR-swizzle replaces the 136-pad (gll needs linear LDS dest;
//     linear [64][256B] rows are 16-way conflicts): prep permutes each
//     row's 16B blocks j -> j^(n&7); kernel stages linearly, reads with
//     the same XOR. 64 lanes spread uniformly over all 8 bank groups.
//  Everything else R17 VERBATIM. LDS ~36 KB -> 3 blocks/CU (R10's best).
// Verified-correct conventions (R8-R17 absmax 0):
//   A-frag: A[m=lane&15][k=quad*8+j]; B-frag: B[n=lane&15][k=quad*8+j];
//   C/D:    col=lane&15 (codeword), row=quad*4+reg (x-row).

typedef _Float16 half8 __attribute__((ext_vector_type(8)));
typedef float    floatx4 __attribute__((ext_vector_type(4)));

#define NVEC  262144
#define DDIM  64
#define KCW   512
#define LOSS_SCALE (0.25f / 16777216.0f)
#define DMARGIN 0.005f
#define BROWS 128
#define NBLK  (NVEC / BROWS)     // 2048
#define CHUNK 64                 // codewords per LDS chunk (8 chunks)

#if defined(__has_builtin)
#if __has_builtin(__builtin_amdgcn_global_load_lds)
#define HAS_GLL 1
#endif
#endif

// d_ws layout (re-poisoned every call -> prep rewrites everything):
#define WS_CSQ   0          // f32[512]
#define WS_CSQH  2048       // f32[512]  (0.5*csq)
#define WS_HL    8192       // f16[512*128]: row n = 16 x 16B blocks,
                            // block j stored at slot j^(n&7) (T2 swizzle)

__global__ void prep_kernel(const float* __restrict__ cw,
                            float* __restrict__ csq,
                            float* __restrict__ csqh,
                            _Float16* __restrict__ cw_hl,
                            float* __restrict__ loss_slot) {
    int n = blockIdx.x * blockDim.x + threadIdx.x;
    if (n < KCW) {
        const float4* r = (const float4*)(cw + n * DDIM);
        _Float16* orow = cw_hl + n * 128;
        const int kx = n & 7;
        float s = 0.f;
        #pragma unroll
        for (int t = 0; t < 8; ++t) {
            float4 a = r[2 * t], b = r[2 * t + 1];
            half8 hh, ll;
            #pragma unroll
            for (int i = 0; i < 4; ++i) {
                float v = ((const float*)&a)[i];
                s += v * v;
                _Float16 h = (_Float16)v;
                hh[i] = h; ll[i] = (_Float16)(v - (float)h);
                v = ((const float*)&b)[i];
                s += v * v;
                h = (_Float16)v;
                hh[4 + i] = h; ll[4 + i] = (_Float16)(v - (float)h);
            }
            // logical block t (hi) -> slot t^kx; block 8+t (lo) -> (8+t)^kx
            *(half8*)(orow + ((t ^ kx) << 3))       = hh;
            *(half8*)(orow + (((8 + t) ^ kx) << 3)) = ll;
        }
        csq[n]  = s;
        csqh[n] = 0.5f * s;
    }
    if (n == 0) *loss_slot = 0.f;
}

__global__ void vq_mfma_kernel(const float* __restrict__ x,
                               const float* __restrict__ cw,
                               const _Float16* __restrict__ cw_hl,
                               const float* __restrict__ csqh,
                               const float* __restrict__ csq,
                               float* __restrict__ out_q,
                               float* __restrict__ out_idx,
                               float* __restrict__ out_loss) {
    // two linear 16 KB chunk buffers (64 cw x 256 B), no pad (swizzled)
    __shared__ __align__(16) _Float16 Bs[2 * CHUNK * 128];   // 32768 B
    __shared__ float         csqhs[KCW];                     // 2048 B
    __shared__ int           win[BROWS];
    __shared__ int           lslist[BROWS];
    __shared__ unsigned char flg[BROWS];
    __shared__ float         red[4];
    __shared__ unsigned      lcnt;

    const int tid  = threadIdx.x;
    const int w    = tid >> 6;
    const int lane = tid & 63;
    const int quad = lane >> 4;
    const int col  = lane & 15;
    const int blk  = blockIdx.x * BROWS;
    char* BsB = (char*)Bs;

    if (tid == 0) lcnt = 0u;
    csqhs[tid]       = -csqh[tid];
    csqhs[tid + 256] = -csqh[tid + 256];

    // ---- a-frags: 2 row-tiles/wave (32 rows), hi/lo split, in-register ----
    half8 ah0[2], ah1[2], al0[2], al1[2];
    #pragma unroll
    for (int rt = 0; rt < 2; ++rt) {
        const float* xr = x + (size_t)(blk + w * 32 + rt * 16 + col) * DDIM;
        float4 f0 = *(const float4*)(xr + quad * 8);
        float4 f1 = *(const float4*)(xr + quad * 8 + 4);
        float4 g0 = *(const float4*)(xr + 32 + quad * 8);
        float4 g1 = *(const float4*)(xr + 32 + quad * 8 + 4);
        #pragma unroll
        for (int i = 0; i < 4; ++i) {
            float v = ((const float*)&f0)[i];
            _Float16 h = (_Float16)v;
            ah0[rt][i] = h; al0[rt][i] = (_Float16)(v - (float)h);
            v = ((const float*)&f1)[i]; h = (_Float16)v;
            ah0[rt][4 + i] = h; al0[rt][4 + i] = (_Float16)(v - (float)h);
            v = ((const float*)&g0)[i]; h = (_Float16)v;
            ah1[rt][i] = h; al1[rt][i] = (_Float16)(v - (float)h);
            v = ((const float*)&g1)[i]; h = (_Float16)v;
            ah1[rt][4 + i] = h; al1[rt][4 + i] = (_Float16)(v - (float)h);
        }
    }

    float M1[8], M2[8];
    int   idx[8];
    #pragma unroll
    for (int s = 0; s < 8; ++s) {
        M1[s] = -3.402823466e38f; M2[s] = -3.402823466e38f; idx[s] = 0;
    }

    // stage chunk ch into buffer b: linear 16 KB copy, 4 KB per wave
    auto STAGE = [&](int b, int ch) {
#ifdef HAS_GLL
        const char* g = (const char*)cw_hl + (ch << 14) + (w << 12) + (lane << 4);
        const char* l = BsB + (b << 14) + (w << 12);
        #pragma unroll
        for (int k = 0; k < 4; ++k) {
            __builtin_amdgcn_global_load_lds(
                (const __attribute__((address_space(1))) void*)(g + (k << 10)),
                (__attribute__((address_space(3))) void*)(l + (k << 10)),
                16, 0, 0);
        }
#else
        const char* g = (const char*)cw_hl + (ch << 14) + (w << 12) + (lane << 4);
        char* l = BsB + (b << 14) + (w << 12) + (lane << 4);
        #pragma unroll
        for (int k = 0; k < 4; ++k)
            *(half8*)(l + (k << 10)) = *(const half8*)(g + (k << 10));
#endif
    };

    // ---- scan 512 codewords: 8 chunks, double-buffered, 1 barrier/chunk ----
    STAGE(0, 0);
    const int kx = col & 7;                      // read-side T2 swizzle key
    int cur = 0;
    #pragma unroll 1
    for (int ch = 0; ch < 8; ++ch) {
        asm volatile("s_waitcnt vmcnt(0)" ::: "memory");  // own stage landed
        __syncthreads();   // all waves' stage landed; prior buf reads done
        if (ch < 7) STAGE(cur ^ 1, ch + 1);      // fire-and-forget next chunk

        #pragma unroll 2
        for (int t = 0; t < 4; ++t) {
            const int n    = ch * CHUNK + t * 16 + col;
            const char* rb = BsB + (cur << 14) + ((t * 16 + col) << 8);
            half8 bh0 = *(const half8*)(rb + (((quad)      ^ kx) << 4));
            half8 bh1 = *(const half8*)(rb + (((4  + quad) ^ kx) << 4));
            half8 bl0 = *(const half8*)(rb + (((8  + quad) ^ kx) << 4));
            half8 bl1 = *(const half8*)(rb + (((12 + quad) ^ kx) << 4));
            const float vn = csqhs[n];                   // = -0.5*csq[n]

            #pragma unroll
            for (int rt = 0; rt < 2; ++rt) {
                floatx4 acc = {vn, vn, vn, vn};          // bias folded into C
                acc = __builtin_amdgcn_mfma_f32_16x16x32_f16(ah0[rt], bh0, acc, 0, 0, 0);
                acc = __builtin_amdgcn_mfma_f32_16x16x32_f16(ah1[rt], bh1, acc, 0, 0, 0);
                acc = __builtin_amdgcn_mfma_f32_16x16x32_f16(al0[rt], bh0, acc, 0, 0, 0);
                acc = __builtin_amdgcn_mfma_f32_16x16x32_f16(al1[rt], bh1, acc, 0, 0, 0);
                acc = __builtin_amdgcn_mfma_f32_16x16x32_f16(ah0[rt], bl0, acc, 0, 0, 0);
                acc = __builtin_amdgcn_mfma_f32_16x16x32_f16(ah1[rt], bl1, acc, 0, 0, 0);
                #pragma unroll
                for (int reg = 0; reg < 4; ++reg) {
                    int s = rt * 4 + reg;
                    float d = acc[reg];                  // dot - 0.5*csq (max)
                    if (d > M1[s]) idx[s] = n;           // strict >: first-max
                    M2[s] = __builtin_amdgcn_fmed3f(M1[s], M2[s], d);
                    M1[s] = fmaxf(M1[s], d);
                }
            }
        }
        cur ^= 1;
    }

    // ---- cross-lane (M1, idx, M2) reduce over the 16 cols of each quad ----
    #pragma unroll
    for (int off = 1; off < 16; off <<= 1) {
        #pragma unroll
        for (int s = 0; s < 8; ++s) {
            float o1 = __shfl_xor(M1[s], off, 16);
            float o2 = __shfl_xor(M2[s], off, 16);
            int   oi = __shfl_xor(idx[s], off, 16);
            float mn = fminf(M1[s], o1);             // loser of the two leaders
            M2[s] = fmaxf(fmaxf(M2[s], o2), mn);
            if (o1 > M1[s] || (o1 == M1[s] && oi < idx[s])) idx[s] = oi;
            M1[s] = fmaxf(M1[s], o1);
        }
    }

    // ---- phase A: winners, flags, block-local flagged list ----
    if (col < 4) {   // lane col handles reg=col for both row-tiles
        #pragma unroll
        for (int rt = 0; rt < 2; ++rt) {
            int s  = rt * 4 + col;
            int rl = w * 32 + rt * 16 + quad * 4 + col;
            int nw = idx[s];
            int f  = (M1[s] - M2[s] <= DMARGIN) ? 1 : 0;
            win[rl] = nw;
            flg[rl] = (unsigned char)f;
            out_idx[blk + rl] = (float)nw;           // flagged rows fixed below
            if (f) { unsigned p = atomicAdd(&lcnt, 1u); lslist[p] = rl; }
        }
    }
    __syncthreads();

    // ---- phase B: dense quantized write + commitment loss (skip flagged) ----
    float ls = 0.f;
    #pragma unroll
    for (int k = 0; k < 8; ++k) {
        int rl = k * 16 + (tid >> 4);
        int e4 = (tid & 15) * 4;                     // lane-contiguous 16 B
        int wn = win[rl];
        int f  = flg[rl];
        float4 q  = *(const float4*)(cw + wn * DDIM + e4);   // L1/L2-hot
        float4 xv = *(const float4*)(x + (size_t)(blk + rl) * DDIM + e4);
        *(float4*)(out_q + (size_t)(blk + rl) * DDIM + e4) = q;  // dense store
        if (!f) {
            float d0 = q.x - xv.x, d1 = q.y - xv.y;
            float d2 = q.z - xv.z, d3 = q.w - xv.w;
            ls += d0 * d0 + d1 * d1 + d2 * d2 + d3 * d3;
        }
    }
    #pragma unroll
    for (int off = 32; off > 0; off >>= 1) ls += __shfl_down(ls, off, 64);
    if (lane == 0) red[w] = ls;
    __syncthreads();   // also orders phase-B stores before phase-C rewrites
    if (tid == 0)
        atomicAdd(out_loss, ((red[0] + red[1]) + (red[2] + red[3])) * LOSS_SCALE);

    // ---- phase C: fused exact-fp32 rescan of flagged rows ----
    const unsigned cnt = lcnt;
    const int grp = tid >> 4;
    const int tx  = tid & 15;
    for (unsigned i = (unsigned)grp; i < cnt; i += 16) {
        const int rl = lslist[i];
        const size_t row = (size_t)blk + rl;

        float4 xr[16];
        const float4* xg = (const float4*)(x + row * DDIM);
        #pragma unroll
        for (int t = 0; t < 16; ++t) xr[t] = xg[t];

        float best = 3.402823466e38f; int bi = 0;
        for (int j = 0; j < 32; ++j) {
            int n = tx + 16 * j;                     // ascending per lane
            const float4* c = (const float4*)(cw + n * DDIM);
            float a0 = 0.f, a1 = 0.f, a2 = 0.f, a3 = 0.f;
            #pragma unroll
            for (int t = 0; t < 16; ++t) {
                float4 cv = c[t];
                a0 = __builtin_fmaf(xr[t].x, cv.x, a0);
                a1 = __builtin_fmaf(xr[t].y, cv.y, a1);
                a2 = __builtin_fmaf(xr[t].z, cv.z, a2);
                a3 = __builtin_fmaf(xr[t].w, cv.w, a3);
            }
            float sc = __builtin_fmaf(-2.f, (a0 + a1) + (a2 + a3), csq[n]);
            if (sc < best) { best = sc; bi = n; }
        }
        #pragma unroll
        for (int off = 8; off > 0; off >>= 1) {
            float d2 = __shfl_down(best, off, 16);
            int   i2 = __shfl_down(bi,   off, 16);
            if (d2 < best || (d2 == best && i2 < bi)) { best = d2; bi = i2; }
        }
        if (tx == 0) {
            out_idx[row] = (float)bi;
            const float4* qg = (const float4*)(cw + bi * DDIM);
            float4* og = (float4*)(out_q + row * DDIM);
            float lf = 0.f;
            #pragma unroll
            for (int t = 0; t < 16; ++t) {
                float4 q = qg[t];
                og[t] = q;
                float d0 = q.x - xr[t].x, d1 = q.y - xr[t].y;
                float d2_ = q.z - xr[t].z, d3 = q.w - xr[t].w;
                lf += d0 * d0 + d1 * d1 + d2_ * d2_ + d3 * d3;
            }
            atomicAdd(out_loss, lf * LOSS_SCALE);
        }
    }
}

extern "C" void kernel_launch(void* const* d_in, const int* in_sizes, int n_in,
                              void* d_out, int out_size, void* d_ws, size_t ws_size,
                              hipStream_t stream) {
    const float* x  = (const float*)d_in[0];   // (64,4096,64) fp32
    const float* cw = (const float*)d_in[1];   // (512,64) fp32
    float* out      = (float*)d_out;
    float* out_q    = out;                      // 16777216
    float* out_idx  = out + 16777216;           // 262144
    float* out_loss = out + 16777216 + 262144;  // 1

    char* ws = (char*)d_ws;
    float*    csq   = (float*)(ws + WS_CSQ);
    float*    csqh  = (float*)(ws + WS_CSQH);
    _Float16* cw_hl = (_Float16*)(ws + WS_HL);

    prep_kernel<<<2, 256, 0, stream>>>(cw, csq, csqh, cw_hl, out_loss);
    vq_mfma_kernel<<<NBLK, 256, 0, stream>>>(x, cw, cw_hl, csqh, csq,
                                             out_q, out_idx, out_loss);
}